// Round 2
// baseline (256.761 us; speedup 1.0000x reference)
//
#include <hip/hip_runtime.h>
#include <stdint.h>

typedef __attribute__((ext_vector_type(4))) float  float4v;
typedef __attribute__((ext_vector_type(8))) __bf16 bf16x8;
typedef __attribute__((ext_vector_type(8))) unsigned short ushort8;
typedef __attribute__((ext_vector_type(4))) unsigned short ushort4v;

#define B_DIM 8192
#define H_DIM 1024
#define O_DIM 1024

static __device__ __forceinline__ unsigned short f32_to_bf16(float f) {
  union { float f; unsigned int u; } v; v.f = f;
  unsigned int u = v.u;
  unsigned int r = u + 0x7FFFu + ((u >> 16) & 1u);  // round-to-nearest-even
  return (unsigned short)(r >> 16);
}

// ---------------------------------------------------------------------------
// coeff[m][b]: m=0..3 -> mix*softmax_m ; m=4 -> (1-mix)
// ---------------------------------------------------------------------------
__global__ void prep_coeff(const float* __restrict__ se, const float* __restrict__ curv,
                           const float* __restrict__ gw, const float* __restrict__ gb,
                           float* __restrict__ cfg) {
  int b = blockIdx.x * blockDim.x + threadIdx.x;
  if (b >= B_DIM) return;
  float s = se[b];
  float l0 = s * gw[0] + gb[0];
  float l1 = s * gw[1] + gb[1];
  float l2 = s * gw[2] + gb[2];
  float l3 = s * gw[3] + gb[3];
  float mx = fmaxf(fmaxf(l0, l1), fmaxf(l2, l3));
  float e0 = __expf(l0 - mx), e1 = __expf(l1 - mx), e2 = __expf(l2 - mx), e3 = __expf(l3 - mx);
  float mix = 1.0f / (1.0f + __expf(-curv[b]));
  float inv = mix / (e0 + e1 + e2 + e3);
  cfg[0 * B_DIM + b] = e0 * inv;
  cfg[1 * B_DIM + b] = e1 * inv;
  cfg[2 * B_DIM + b] = e2 * inv;
  cfg[3 * B_DIM + b] = e3 * inv;
  cfg[4 * B_DIM + b] = 1.0f - mix;
}

// ---------------------------------------------------------------------------
// state fp32 [B][H] -> bf16 [B][H]   (8 elems/thread, 16B stores)
// ---------------------------------------------------------------------------
__global__ void cast_state(const float* __restrict__ src, unsigned short* __restrict__ dst, int n8) {
  int i = blockIdx.x * blockDim.x + threadIdx.x;
  if (i >= n8) return;
  float4v v0 = ((const float4v*)src)[i * 2];
  float4v v1 = ((const float4v*)src)[i * 2 + 1];
  ushort8 o;
  o[0] = f32_to_bf16(v0.x); o[1] = f32_to_bf16(v0.y);
  o[2] = f32_to_bf16(v0.z); o[3] = f32_to_bf16(v0.w);
  o[4] = f32_to_bf16(v1.x); o[5] = f32_to_bf16(v1.y);
  o[6] = f32_to_bf16(v1.z); o[7] = f32_to_bf16(v1.w);
  ((ushort8*)dst)[i] = o;
}

// ---------------------------------------------------------------------------
// basis [4][H][O] + prj_w [H][O]  ->  Wt bf16 [5][O][H]   (LDS-tiled transpose)
// grid: (O/64, H/64, 5), block 256
// ---------------------------------------------------------------------------
__global__ void transpose_cast(const float* __restrict__ basis, const float* __restrict__ prjw,
                               unsigned short* __restrict__ Wt) {
  __shared__ __align__(16) unsigned short t[64 * 72];  // pad 8 shorts/row (16B-aligned rows)
  int m = blockIdx.z;
  const float* src = (m < 4) ? (basis + (size_t)m * H_DIM * O_DIM) : prjw;  // [H][O]
  int o0 = blockIdx.x * 64, h0 = blockIdx.y * 64;
  int tid = threadIdx.x;
  int r  = tid >> 4;          // 0..15
  int c4 = (tid & 15) * 4;    // 0..60
#pragma unroll
  for (int p = 0; p < 4; ++p) {
    int h = r + p * 16;
    float4v v = *(const float4v*)(src + (size_t)(h0 + h) * O_DIM + o0 + c4);
    t[(c4 + 0) * 72 + h] = f32_to_bf16(v.x);
    t[(c4 + 1) * 72 + h] = f32_to_bf16(v.y);
    t[(c4 + 2) * 72 + h] = f32_to_bf16(v.z);
    t[(c4 + 3) * 72 + h] = f32_to_bf16(v.w);
  }
  __syncthreads();
#pragma unroll
  for (int i = 0; i < 2; ++i) {
    int C = i * 256 + tid;        // 0..511 : 64 rows x 8 chunks
    int o = C >> 3, cc = C & 7;
    ushort8 val = *(const ushort8*)(t + o * 72 + cc * 8);
    *(ushort8*)(Wt + ((size_t)m * O_DIM + o0 + o) * H_DIM + h0 + cc * 8) = val;
  }
}

// ---------------------------------------------------------------------------
// Fused 5-mode GEMM + combine.
//  A  bf16 [B][H] ; Wt bf16 [5][O][H] ; cfg [5][B] ; out fp32 [B][O]
//  Block tile 128(B) x 64(O), 4 waves in 2x2, each wave 64x32 (4x2 mfma frags).
//  Grid (64,16) = 1024 blocks = 4 blocks/CU (occupancy was the R1 bottleneck).
//  global_load_lds(16B) staging; XOR swizzle (chunk ^= row&7) on the fetch side
//  keeps all frag ds_read_b128s conflict-free (R1: SQ_LDS_BANK_CONFLICT == 0).
// ---------------------------------------------------------------------------
__global__ __launch_bounds__(256, 4)
void gemm_fused(const unsigned short* __restrict__ A,
                const unsigned short* __restrict__ Wt,
                const float* __restrict__ cfg,
                const float* __restrict__ prjb,
                float* __restrict__ out) {
  __shared__ __align__(16) unsigned short sA[128 * 64];  // 16 KB
  __shared__ __align__(16) unsigned short sB[64 * 64];   //  8 KB
  __shared__ __align__(16) float scf[5 * 128];           // 2.5 KB

  const int tid  = threadIdx.x;
  const int lane = tid & 63;
  const int wave = tid >> 6;
  const int row0 = blockIdx.x * 128;
  const int col0 = blockIdx.y * 64;
  const int wrow = (wave >> 1) * 64;   // 0 or 64
  const int wcol = (wave & 1) * 32;    // 0 or 32
  const int q  = lane >> 4;   // quad 0..3
  const int ln = lane & 15;

  for (int i = tid; i < 5 * 128; i += 256)
    scf[i] = cfg[(i >> 7) * B_DIM + row0 + (i & 127)];

  // staging patterns (16B chunks, XOR swizzle on the global fetch side)
  int arow[4], acol[4];
#pragma unroll
  for (int j = 0; j < 4; ++j) {
    int L = (wave * 4 + j) * 64 + lane;   // 0..1023
    arow[j] = L >> 3;
    acol[j] = (L & 7) ^ (arow[j] & 7);
  }
  int brow[2], bcol[2];
#pragma unroll
  for (int j = 0; j < 2; ++j) {
    int L = (wave * 2 + j) * 64 + lane;   // 0..511
    brow[j] = L >> 3;
    bcol[j] = (L & 7) ^ (brow[j] & 7);
  }

  float4v acc[4][2];
  float4v oacc[4][2];
#pragma unroll
  for (int i = 0; i < 4; ++i)
#pragma unroll
    for (int j = 0; j < 2; ++j)
      oacc[i][j] = (float4v){0.f, 0.f, 0.f, 0.f};

  for (int mode = 0; mode < 5; ++mode) {
#pragma unroll
    for (int i = 0; i < 4; ++i)
#pragma unroll
      for (int j = 0; j < 2; ++j)
        acc[i][j] = (float4v){0.f, 0.f, 0.f, 0.f};

    const unsigned short* Wm = Wt + (size_t)mode * O_DIM * H_DIM;

    for (int kt = 0; kt < 16; ++kt) {
      const int k0 = kt * 64;
      __syncthreads();  // previous compute done before LDS overwrite
#pragma unroll
      for (int j = 0; j < 4; ++j) {
        const unsigned short* ga = A + (size_t)(row0 + arow[j]) * H_DIM + k0 + acol[j] * 8;
        unsigned short* la = sA + (wave * 4 + j) * 512;  // wave-uniform LDS base
        __builtin_amdgcn_global_load_lds(
            (const __attribute__((address_space(1))) void*)ga,
            (__attribute__((address_space(3))) void*)la, 16, 0, 0);
      }
#pragma unroll
      for (int j = 0; j < 2; ++j) {
        const unsigned short* gw = Wm + (size_t)(col0 + brow[j]) * H_DIM + k0 + bcol[j] * 8;
        unsigned short* lb = sB + (wave * 2 + j) * 512;
        __builtin_amdgcn_global_load_lds(
            (const __attribute__((address_space(1))) void*)gw,
            (__attribute__((address_space(3))) void*)lb, 16, 0, 0);
      }
      __syncthreads();  // vmcnt(0) drain + barrier

#pragma unroll
      for (int kk = 0; kk < 2; ++kk) {
        bf16x8 af[4], bfr[2];
#pragma unroll
        for (int t = 0; t < 4; ++t) {
          int ra = wrow + t * 16 + ln;
          int ca = (kk * 4 + q) ^ (ra & 7);
          af[t] = *(const bf16x8*)(sA + ra * 64 + ca * 8);
        }
#pragma unroll
        for (int t = 0; t < 2; ++t) {
          int rb = wcol + t * 16 + ln;
          int cb = (kk * 4 + q) ^ (rb & 7);
          bfr[t] = *(const bf16x8*)(sB + rb * 64 + cb * 8);
        }
#pragma unroll
        for (int ti = 0; ti < 4; ++ti)
#pragma unroll
          for (int tj = 0; tj < 2; ++tj)
            acc[ti][tj] = __builtin_amdgcn_mfma_f32_16x16x32_bf16(
                af[ti], bfr[tj], acc[ti][tj], 0, 0, 0);
      }
    }

    // oacc += coeff[mode][row] * acc   (C/D layout: row = q*4 + reg, col = ln)
#pragma unroll
    for (int ti = 0; ti < 4; ++ti) {
      int rl = wrow + ti * 16 + q * 4;
      float4v c4 = *(const float4v*)(scf + mode * 128 + rl);
#pragma unroll
      for (int tj = 0; tj < 2; ++tj)
        oacc[ti][tj] += c4 * acc[ti][tj];
    }
  }

  // epilogue: + (1-mix)*prj_b , store
#pragma unroll
  for (int ti = 0; ti < 4; ++ti) {
    int rl = wrow + ti * 16 + q * 4;
    float4v cb = *(const float4v*)(scf + 4 * 128 + rl);
#pragma unroll
    for (int tj = 0; tj < 2; ++tj) {
      int col = col0 + wcol + tj * 16 + ln;
      float pb = prjb[col];
      float4v v = oacc[ti][tj] + cb * pb;
      size_t base = (size_t)(row0 + rl) * O_DIM + col;
      out[base]             = v.x;
      out[base + O_DIM]     = v.y;
      out[base + 2 * O_DIM] = v.z;
      out[base + 3 * O_DIM] = v.w;
    }
  }
}

// ---------------------------------------------------------------------------
extern "C" void kernel_launch(void* const* d_in, const int* in_sizes, int n_in,
                              void* d_out, int out_size, void* d_ws, size_t ws_size,
                              hipStream_t stream) {
  const float* state = (const float*)d_in[0];
  const float* se    = (const float*)d_in[1];
  const float* curv  = (const float*)d_in[2];
  const float* basis = (const float*)d_in[3];
  const float* gw    = (const float*)d_in[4];
  const float* gb    = (const float*)d_in[5];
  const float* prjw  = (const float*)d_in[6];
  const float* prjb  = (const float*)d_in[7];
  float* out = (float*)d_out;

  char* ws = (char*)d_ws;
  unsigned short* Abf = (unsigned short*)ws;                               // 16 MB
  unsigned short* Wt  = (unsigned short*)(ws + (size_t)16 * 1024 * 1024);  // 10 MB
  float* cfg          = (float*)(ws + (size_t)28 * 1024 * 1024);           // 160 KB

  prep_coeff<<<B_DIM / 256, 256, 0, stream>>>(se, curv, gw, gb, cfg);
  cast_state<<<(B_DIM * H_DIM / 8) / 256, 256, 0, stream>>>(state, Abf, B_DIM * H_DIM / 8);
  dim3 tg(O_DIM / 64, H_DIM / 64, 5);
  transpose_cast<<<tg, 256, 0, stream>>>(basis, prjw, Wt);
  dim3 gg(B_DIM / 128, O_DIM / 64);
  gemm_fused<<<gg, 256, 0, stream>>>(Abf, Wt, cfg, prjb, out);
}

// Round 3
// 183.984 us; speedup vs baseline: 1.3956x; 1.3956x over previous
//
#include <hip/hip_runtime.h>
#include <stdint.h>

typedef __attribute__((ext_vector_type(4))) float  float4v;
typedef __attribute__((ext_vector_type(8))) __bf16 bf16x8;
typedef __attribute__((ext_vector_type(8))) unsigned short ushort8;

#define B_DIM 8192
#define H_DIM 1024
#define O_DIM 1024

static __device__ __forceinline__ unsigned short f32_to_bf16(float f) {
  union { float f; unsigned int u; } v; v.f = f;
  unsigned int u = v.u;
  unsigned int r = u + 0x7FFFu + ((u >> 16) & 1u);  // round-to-nearest-even
  return (unsigned short)(r >> 16);
}

// ---------------------------------------------------------------------------
// coeff[m][b]: m=0..3 -> mix*softmax_m ; m=4 -> (1-mix)
// ---------------------------------------------------------------------------
__global__ void prep_coeff(const float* __restrict__ se, const float* __restrict__ curv,
                           const float* __restrict__ gw, const float* __restrict__ gb,
                           float* __restrict__ cfg) {
  int b = blockIdx.x * blockDim.x + threadIdx.x;
  if (b >= B_DIM) return;
  float s = se[b];
  float l0 = s * gw[0] + gb[0];
  float l1 = s * gw[1] + gb[1];
  float l2 = s * gw[2] + gb[2];
  float l3 = s * gw[3] + gb[3];
  float mx = fmaxf(fmaxf(l0, l1), fmaxf(l2, l3));
  float e0 = __expf(l0 - mx), e1 = __expf(l1 - mx), e2 = __expf(l2 - mx), e3 = __expf(l3 - mx);
  float mix = 1.0f / (1.0f + __expf(-curv[b]));
  float inv = mix / (e0 + e1 + e2 + e3);
  cfg[0 * B_DIM + b] = e0 * inv;
  cfg[1 * B_DIM + b] = e1 * inv;
  cfg[2 * B_DIM + b] = e2 * inv;
  cfg[3 * B_DIM + b] = e3 * inv;
  cfg[4 * B_DIM + b] = 1.0f - mix;
}

// ---------------------------------------------------------------------------
// state fp32 [B][H] -> bf16 [B][H]   (8 elems/thread, 16B stores)
// ---------------------------------------------------------------------------
__global__ void cast_state(const float* __restrict__ src, unsigned short* __restrict__ dst, int n8) {
  int i = blockIdx.x * blockDim.x + threadIdx.x;
  if (i >= n8) return;
  float4v v0 = ((const float4v*)src)[i * 2];
  float4v v1 = ((const float4v*)src)[i * 2 + 1];
  ushort8 o;
  o[0] = f32_to_bf16(v0.x); o[1] = f32_to_bf16(v0.y);
  o[2] = f32_to_bf16(v0.z); o[3] = f32_to_bf16(v0.w);
  o[4] = f32_to_bf16(v1.x); o[5] = f32_to_bf16(v1.y);
  o[6] = f32_to_bf16(v1.z); o[7] = f32_to_bf16(v1.w);
  ((ushort8*)dst)[i] = o;
}

// ---------------------------------------------------------------------------
// basis [4][H][O] + prj_w [H][O]  ->  Wt bf16 [5][O][H]   (LDS-tiled transpose)
// ---------------------------------------------------------------------------
__global__ void transpose_cast(const float* __restrict__ basis, const float* __restrict__ prjw,
                               unsigned short* __restrict__ Wt) {
  __shared__ __align__(16) unsigned short t[64 * 72];
  int m = blockIdx.z;
  const float* src = (m < 4) ? (basis + (size_t)m * H_DIM * O_DIM) : prjw;  // [H][O]
  int o0 = blockIdx.x * 64, h0 = blockIdx.y * 64;
  int tid = threadIdx.x;
  int r  = tid >> 4;
  int c4 = (tid & 15) * 4;
#pragma unroll
  for (int p = 0; p < 4; ++p) {
    int h = r + p * 16;
    float4v v = *(const float4v*)(src + (size_t)(h0 + h) * O_DIM + o0 + c4);
    t[(c4 + 0) * 72 + h] = f32_to_bf16(v.x);
    t[(c4 + 1) * 72 + h] = f32_to_bf16(v.y);
    t[(c4 + 2) * 72 + h] = f32_to_bf16(v.z);
    t[(c4 + 3) * 72 + h] = f32_to_bf16(v.w);
  }
  __syncthreads();
#pragma unroll
  for (int i = 0; i < 2; ++i) {
    int C = i * 256 + tid;
    int o = C >> 3, cc = C & 7;
    ushort8 val = *(const ushort8*)(t + o * 72 + cc * 8);
    *(ushort8*)(Wt + ((size_t)m * O_DIM + o0 + o) * H_DIM + h0 + cc * 8) = val;
  }
}

// ---------------------------------------------------------------------------
// Fused 5-mode GEMM, multimode K-loop.
//  Tile 128(B) x 64(O); waves 2x2, wave-tile 64x32 (4x2 frags of 16x16x32).
//  Per kt: stage A once (16 KB) + B for all 5 modes (40 KB); 80 MFMA/wave per
//  barrier (5x amortization vs R1/R2 — staging-transfer was the bound).
//  acc[5][4][2] register sets; combine with per-row coeffs in epilogue;
//  LDS-repack then float4 full-line stores (R2 WRITE_SIZE 197MB -> ~34MB).
// ---------------------------------------------------------------------------
__global__ __launch_bounds__(256, 2)
void gemm_fused(const unsigned short* __restrict__ A,
                const unsigned short* __restrict__ Wt,
                const float* __restrict__ cfg,
                const float* __restrict__ prjb,
                float* __restrict__ out) {
  __shared__ __align__(16) unsigned char smem[59904];
  unsigned short* sA  = (unsigned short*)smem;             // 128x64 bf16 = 16384 B
  unsigned short* sB  = (unsigned short*)(smem + 16384);   // 5 x 64x64 bf16 = 40960 B
  float*          scf = (float*)(smem + 57344);            // 5 x 128 fp32 = 2560 B

  const int tid  = threadIdx.x;
  const int lane = tid & 63;
  const int wave = tid >> 6;
  const int row0 = blockIdx.x * 128;
  const int col0 = blockIdx.y * 64;
  const int wrow = (wave >> 1) * 64;   // 0 or 64
  const int wcol = (wave & 1) * 32;    // 0 or 32
  const int q  = lane >> 4;
  const int ln = lane & 15;

  for (int i = tid; i < 5 * 128; i += 256)
    scf[i] = cfg[(i >> 7) * B_DIM + row0 + (i & 127)];

  // staging patterns (16B chunks, XOR swizzle chunk^=row&7 on the fetch side)
  int arow[4], acol[4];
#pragma unroll
  for (int j = 0; j < 4; ++j) {
    int L = (wave * 4 + j) * 64 + lane;   // 0..1023 -> 128 rows x 8 chunks
    arow[j] = L >> 3;
    acol[j] = (L & 7) ^ (arow[j] & 7);
  }
  int brow[2], bcol[2];
#pragma unroll
  for (int j = 0; j < 2; ++j) {
    int L = (wave * 2 + j) * 64 + lane;   // 0..511 -> 64 rows x 8 chunks
    brow[j] = L >> 3;
    bcol[j] = (L & 7) ^ (brow[j] & 7);
  }

  float4v acc[5][4][2];
#pragma unroll
  for (int m = 0; m < 5; ++m)
#pragma unroll
    for (int i = 0; i < 4; ++i)
#pragma unroll
      for (int j = 0; j < 2; ++j)
        acc[m][i][j] = (float4v){0.f, 0.f, 0.f, 0.f};

  for (int kt = 0; kt < 16; ++kt) {
    const int k0 = kt * 64;
    __syncthreads();  // prior phase's frag reads done before LDS overwrite
#pragma unroll
    for (int j = 0; j < 4; ++j) {
      const unsigned short* ga = A + (size_t)(row0 + arow[j]) * H_DIM + k0 + acol[j] * 8;
      unsigned short* la = sA + (wave * 4 + j) * 512;  // wave-uniform base
      __builtin_amdgcn_global_load_lds(
          (const __attribute__((address_space(1))) void*)ga,
          (__attribute__((address_space(3))) void*)la, 16, 0, 0);
    }
#pragma unroll
    for (int m = 0; m < 5; ++m) {
      const unsigned short* Wm = Wt + (size_t)m * O_DIM * H_DIM;
#pragma unroll
      for (int j = 0; j < 2; ++j) {
        const unsigned short* gw = Wm + (size_t)(col0 + brow[j]) * H_DIM + k0 + bcol[j] * 8;
        unsigned short* lb = sB + m * 4096 + (wave * 2 + j) * 512;
        __builtin_amdgcn_global_load_lds(
            (const __attribute__((address_space(1))) void*)gw,
            (__attribute__((address_space(3))) void*)lb, 16, 0, 0);
      }
    }
    __syncthreads();  // drain + barrier

#pragma unroll
    for (int kk = 0; kk < 2; ++kk) {
      bf16x8 af[4];
#pragma unroll
      for (int t = 0; t < 4; ++t) {
        int ra = wrow + t * 16 + ln;
        int ca = (kk * 4 + q) ^ (ra & 7);
        af[t] = *(const bf16x8*)(sA + ra * 64 + ca * 8);
      }
#pragma unroll
      for (int m = 0; m < 5; ++m) {
        bf16x8 b0, b1;
        {
          int rb = wcol + ln;
          int cb = (kk * 4 + q) ^ (rb & 7);
          b0 = *(const bf16x8*)(sB + m * 4096 + rb * 64 + cb * 8);
          int rb1 = wcol + 16 + ln;
          int cb1 = (kk * 4 + q) ^ (rb1 & 7);
          b1 = *(const bf16x8*)(sB + m * 4096 + rb1 * 64 + cb1 * 8);
        }
#pragma unroll
        for (int ti = 0; ti < 4; ++ti) {
          acc[m][ti][0] = __builtin_amdgcn_mfma_f32_16x16x32_bf16(af[ti], b0, acc[m][ti][0], 0, 0, 0);
          acc[m][ti][1] = __builtin_amdgcn_mfma_f32_16x16x32_bf16(af[ti], b1, acc[m][ti][1], 0, 0, 0);
        }
      }
    }
  }

  // ---- epilogue: mode-combine -> LDS repack (fp32, pitch 68) -> float4 stores
  __syncthreads();  // all frag reads done; reuse sA/sB space as fp32 buffer
  float* fbuf = (float*)smem;  // 128 x 68 fp32 = 34816 B (scf at 57344 safe)
#pragma unroll
  for (int ti = 0; ti < 4; ++ti) {
    int rl = wrow + ti * 16 + q * 4;
#pragma unroll
    for (int tj = 0; tj < 2; ++tj) {
      int cc = wcol + tj * 16 + ln;
#pragma unroll
      for (int r = 0; r < 4; ++r) {
        float v = 0.f;
#pragma unroll
        for (int m = 0; m < 5; ++m)
          v += scf[m * 128 + rl + r] * acc[m][ti][tj][r];
        fbuf[(rl + r) * 68 + cc] = v;
      }
    }
  }
  __syncthreads();
#pragma unroll
  for (int i = 0; i < 8; ++i) {
    int L = i * 256 + tid;          // 2048 float4s = 128 rows x 16
    int row = L >> 4, c4 = L & 15;
    float4v v = *(const float4v*)(fbuf + row * 68 + c4 * 4);
    float cb = scf[4 * 128 + row];
    float4v pb = *(const float4v*)(prjb + col0 + c4 * 4);
    v += cb * pb;
    *(float4v*)(out + (size_t)(row0 + row) * O_DIM + col0 + c4 * 4) = v;
  }
}

// ---------------------------------------------------------------------------
extern "C" void kernel_launch(void* const* d_in, const int* in_sizes, int n_in,
                              void* d_out, int out_size, void* d_ws, size_t ws_size,
                              hipStream_t stream) {
  const float* state = (const float*)d_in[0];
  const float* se    = (const float*)d_in[1];
  const float* curv  = (const float*)d_in[2];
  const float* basis = (const float*)d_in[3];
  const float* gw    = (const float*)d_in[4];
  const float* gb    = (const float*)d_in[5];
  const float* prjw  = (const float*)d_in[6];
  const float* prjb  = (const float*)d_in[7];
  float* out = (float*)d_out;

  char* ws = (char*)d_ws;
  unsigned short* Abf = (unsigned short*)ws;                               // 16 MB
  unsigned short* Wt  = (unsigned short*)(ws + (size_t)16 * 1024 * 1024);  // 10 MB
  float* cfg          = (float*)(ws + (size_t)28 * 1024 * 1024);           // 160 KB

  prep_coeff<<<B_DIM / 256, 256, 0, stream>>>(se, curv, gw, gb, cfg);
  cast_state<<<(B_DIM * H_DIM / 8) / 256, 256, 0, stream>>>(state, Abf, B_DIM * H_DIM / 8);
  dim3 tg(O_DIM / 64, H_DIM / 64, 5);
  transpose_cast<<<tg, 256, 0, stream>>>(basis, prjw, Wt);
  dim3 gg(B_DIM / 128, O_DIM / 64);
  gemm_fused<<<gg, 256, 0, stream>>>(Abf, Wt, cfg, prjb, out);
}

// Round 4
// 183.716 us; speedup vs baseline: 1.3976x; 1.0015x over previous
//
#include <hip/hip_runtime.h>
#include <stdint.h>

typedef __attribute__((ext_vector_type(4))) float  float4v;
typedef __attribute__((ext_vector_type(8))) __bf16 bf16x8;
typedef __attribute__((ext_vector_type(8))) unsigned short ushort8;

#define B_DIM 8192
#define H_DIM 1024
#define O_DIM 1024

static __device__ __forceinline__ unsigned short f32_to_bf16(float f) {
  union { float f; unsigned int u; } v; v.f = f;
  unsigned int u = v.u;
  unsigned int r = u + 0x7FFFu + ((u >> 16) & 1u);  // round-to-nearest-even
  return (unsigned short)(r >> 16);
}

// ---------------------------------------------------------------------------
// prep_inputs: single launch doing both weight transpose and state cast.
//  blocks [0,1280): basis[4][H][O] + prj_w[H][O] -> Wt bf16 [5][O][H]
//  blocks [1280,5376): state fp32 [B][H] -> Abf bf16 [B][H]
// ---------------------------------------------------------------------------
__global__ void prep_inputs(const float* __restrict__ state,
                            const float* __restrict__ basis,
                            const float* __restrict__ prjw,
                            unsigned short* __restrict__ Abf,
                            unsigned short* __restrict__ Wt) {
  __shared__ __align__(16) unsigned short t[64 * 72];
  int bb = blockIdx.x;
  int tid = threadIdx.x;
  if (bb < 1280) {
    int m = bb >> 8, panel = bb & 255;
    int o0 = (panel & 15) * 64, h0 = (panel >> 4) * 64;
    const float* src = (m < 4) ? (basis + (size_t)m * H_DIM * O_DIM) : prjw;  // [H][O]
    int r  = tid >> 4;
    int c4 = (tid & 15) * 4;
#pragma unroll
    for (int p = 0; p < 4; ++p) {
      int h = r + p * 16;
      float4v v = *(const float4v*)(src + (size_t)(h0 + h) * O_DIM + o0 + c4);
      t[(c4 + 0) * 72 + h] = f32_to_bf16(v.x);
      t[(c4 + 1) * 72 + h] = f32_to_bf16(v.y);
      t[(c4 + 2) * 72 + h] = f32_to_bf16(v.z);
      t[(c4 + 3) * 72 + h] = f32_to_bf16(v.w);
    }
    __syncthreads();
#pragma unroll
    for (int i = 0; i < 2; ++i) {
      int C = i * 256 + tid;
      int o = C >> 3, cc = C & 7;
      ushort8 val = *(const ushort8*)(t + o * 72 + cc * 8);
      *(ushort8*)(Wt + ((size_t)m * O_DIM + o0 + o) * H_DIM + h0 + cc * 8) = val;
    }
  } else {
    int i = (bb - 1280) * 256 + tid;  // 8 elems per thread
    float4v v0 = ((const float4v*)state)[i * 2];
    float4v v1 = ((const float4v*)state)[i * 2 + 1];
    ushort8 o;
    o[0] = f32_to_bf16(v0.x); o[1] = f32_to_bf16(v0.y);
    o[2] = f32_to_bf16(v0.z); o[3] = f32_to_bf16(v0.w);
    o[4] = f32_to_bf16(v1.x); o[5] = f32_to_bf16(v1.y);
    o[6] = f32_to_bf16(v1.z); o[7] = f32_to_bf16(v1.w);
    ((ushort8*)Abf)[i] = o;
  }
}

// ---------------------------------------------------------------------------
// Fused 5-mode GEMM, software-pipelined K-loop.
//  Tile 128(B) x 64(O); waves 2x2, wave-tile 64x32. BK=32, 32 stages.
//  Double-buffered LDS (2 x 28KB): issue stage s+1 -> compute stage s ->
//  __syncthreads. The vmcnt drain now lands AFTER a full compute window
//  (R3: drain immediately after issue = 54% stall at MfmaUtil 46%).
//  Chunk swizzle pos = q ^ ((row>>1)&3) on 64B rows: conflict-free b128 reads.
//  Coeff prep fused in (reads se/curv/gate directly; cfg kernel deleted).
// ---------------------------------------------------------------------------
__global__ __launch_bounds__(256, 2)
void gemm_fused(const unsigned short* __restrict__ A,
                const unsigned short* __restrict__ Wt,
                const float* __restrict__ se, const float* __restrict__ curv,
                const float* __restrict__ gw, const float* __restrict__ gb,
                const float* __restrict__ prjb,
                float* __restrict__ out) {
  __shared__ __align__(16) unsigned char smem[59904];
  // stage buf s&1 at s*28672: [A 128x32 bf16 = 8192B][B 5 x 64x32 = 20480B]
  float* scf = (float*)(smem + 57344);  // 5 x 128 fp32

  const int tid  = threadIdx.x;
  const int lane = tid & 63;
  const int wave = tid >> 6;
  const int row0 = blockIdx.x * 128;
  const int col0 = blockIdx.y * 64;
  const int wrow = (wave >> 1) * 64;   // 0 or 64
  const int wcol = (wave & 1) * 32;    // 0 or 32
  const int q  = lane >> 4;
  const int ln = lane & 15;

  // ---- fused coeff prep: coeff[m][row] for this block's 128 rows
  if (tid < 128) {
    int b = row0 + tid;
    float s = se[b];
    float l0 = fmaf(s, gw[0], gb[0]);
    float l1 = fmaf(s, gw[1], gb[1]);
    float l2 = fmaf(s, gw[2], gb[2]);
    float l3 = fmaf(s, gw[3], gb[3]);
    float mx = fmaxf(fmaxf(l0, l1), fmaxf(l2, l3));
    float e0 = __expf(l0 - mx), e1 = __expf(l1 - mx);
    float e2 = __expf(l2 - mx), e3 = __expf(l3 - mx);
    float mix = 1.0f / (1.0f + __expf(-curv[b]));
    float inv = mix / (e0 + e1 + e2 + e3);
    scf[0 * 128 + tid] = e0 * inv;
    scf[1 * 128 + tid] = e1 * inv;
    scf[2 * 128 + tid] = e2 * inv;
    scf[3 * 128 + tid] = e3 * inv;
    scf[4 * 128 + tid] = 1.0f - mix;
  }

  // ---- staging descriptors (16B chunks; stored pos holds global chunk
  //      g = pos ^ ((row>>1)&3); rows are 32 elems = 64B = 4 chunks)
  const unsigned short* gA[2];
  unsigned int ldsA[2];
#pragma unroll
  for (int j = 0; j < 2; ++j) {
    int C = (wave * 2 + j) * 64 + lane;     // 0..511
    int row = C >> 2, pos = C & 3;
    int g = pos ^ ((row >> 1) & 3);
    gA[j] = A + (size_t)(row0 + row) * H_DIM + g * 8;
    ldsA[j] = (wave * 2 + j) * 1024;        // wave-uniform base (HW adds lane*16)
  }
  const unsigned short* gB[5];
  unsigned int ldsBbase = 8192 + wave * 1024;
  {
    int C = wave * 64 + lane;               // 0..255
    int row = C >> 2, pos = C & 3;
    int g = pos ^ ((row >> 1) & 3);
#pragma unroll
    for (int m = 0; m < 5; ++m)
      gB[m] = Wt + (size_t)m * O_DIM * H_DIM + (size_t)(col0 + row) * H_DIM + g * 8;
  }

  float4v acc[5][4][2];
#pragma unroll
  for (int m = 0; m < 5; ++m)
#pragma unroll
    for (int i = 0; i < 4; ++i)
#pragma unroll
      for (int j = 0; j < 2; ++j)
        acc[m][i][j] = (float4v){0.f, 0.f, 0.f, 0.f};

#define ISSUE_STAGE(s)                                                          \
  do {                                                                          \
    const int _buf = (s) & 1;                                                   \
    const int _k = (s) * 32;                                                    \
    unsigned char* _base = smem + _buf * 28672;                                 \
    _Pragma("unroll")                                                           \
    for (int _j = 0; _j < 2; ++_j)                                              \
      __builtin_amdgcn_global_load_lds(                                         \
          (const __attribute__((address_space(1))) void*)(gA[_j] + _k),         \
          (__attribute__((address_space(3))) void*)(_base + ldsA[_j]), 16, 0, 0);\
    _Pragma("unroll")                                                           \
    for (int _m = 0; _m < 5; ++_m)                                              \
      __builtin_amdgcn_global_load_lds(                                         \
          (const __attribute__((address_space(1))) void*)(gB[_m] + _k),         \
          (__attribute__((address_space(3))) void*)(_base + ldsBbase + _m * 4096),\
          16, 0, 0);                                                            \
  } while (0)

#define COMPUTE_STAGE(s)                                                        \
  do {                                                                          \
    const unsigned short* _sA = (const unsigned short*)(smem + ((s) & 1) * 28672);\
    const unsigned short* _sB = _sA + 4096;                                     \
    bf16x8 _af[4];                                                              \
    _Pragma("unroll")                                                           \
    for (int _t = 0; _t < 4; ++_t) {                                            \
      int _ra = wrow + _t * 16 + ln;                                            \
      int _ps = q ^ ((_ra >> 1) & 3);                                           \
      _af[_t] = *(const bf16x8*)(_sA + _ra * 32 + _ps * 8);                     \
    }                                                                           \
    _Pragma("unroll")                                                           \
    for (int _m = 0; _m < 5; ++_m) {                                            \
      bf16x8 _b0, _b1;                                                          \
      {                                                                         \
        int _rb = wcol + ln;                                                    \
        int _p0 = q ^ ((_rb >> 1) & 3);                                         \
        _b0 = *(const bf16x8*)(_sB + _m * 2048 + _rb * 32 + _p0 * 8);           \
        int _r1 = wcol + 16 + ln;                                               \
        int _p1 = q ^ ((_r1 >> 1) & 3);                                         \
        _b1 = *(const bf16x8*)(_sB + _m * 2048 + _r1 * 32 + _p1 * 8);           \
      }                                                                         \
      _Pragma("unroll")                                                         \
      for (int _ti = 0; _ti < 4; ++_ti) {                                       \
        acc[_m][_ti][0] = __builtin_amdgcn_mfma_f32_16x16x32_bf16(              \
            _af[_ti], _b0, acc[_m][_ti][0], 0, 0, 0);                           \
        acc[_m][_ti][1] = __builtin_amdgcn_mfma_f32_16x16x32_bf16(              \
            _af[_ti], _b1, acc[_m][_ti][1], 0, 0, 0);                           \
      }                                                                         \
    }                                                                           \
  } while (0)

  ISSUE_STAGE(0);
  __syncthreads();  // stage 0 landed; scf visible
#pragma unroll 2
  for (int s = 0; s < 31; ++s) {
    ISSUE_STAGE(s + 1);   // prefetch into the other buffer
    COMPUTE_STAGE(s);     // full compute window overlaps the loads
    __syncthreads();      // drain s+1 loads + all waves done reading buf s
  }
  COMPUTE_STAGE(31);

  // ---- epilogue: mode-combine -> LDS repack (fp32, pitch 68) -> float4 stores
  __syncthreads();
  float* fbuf = (float*)smem;  // 128 x 68 fp32 = 34816 B (scf at 57344 safe)
#pragma unroll
  for (int ti = 0; ti < 4; ++ti) {
    int rl = wrow + ti * 16 + q * 4;
#pragma unroll
    for (int tj = 0; tj < 2; ++tj) {
      int cc = wcol + tj * 16 + ln;
#pragma unroll
      for (int r = 0; r < 4; ++r) {
        float v = 0.f;
#pragma unroll
        for (int m = 0; m < 5; ++m)
          v += scf[m * 128 + rl + r] * acc[m][ti][tj][r];
        fbuf[(rl + r) * 68 + cc] = v;
      }
    }
  }
  __syncthreads();
#pragma unroll
  for (int i = 0; i < 8; ++i) {
    int L = i * 256 + tid;          // 2048 float4s = 128 rows x 16
    int row = L >> 4, c4 = L & 15;
    float4v v = *(const float4v*)(fbuf + row * 68 + c4 * 4);
    float cb = scf[4 * 128 + row];
    float4v pb = *(const float4v*)(prjb + col0 + c4 * 4);
    v += cb * pb;
    *(float4v*)(out + (size_t)(row0 + row) * O_DIM + col0 + c4 * 4) = v;
  }
#undef ISSUE_STAGE
#undef COMPUTE_STAGE
}

// ---------------------------------------------------------------------------
extern "C" void kernel_launch(void* const* d_in, const int* in_sizes, int n_in,
                              void* d_out, int out_size, void* d_ws, size_t ws_size,
                              hipStream_t stream) {
  const float* state = (const float*)d_in[0];
  const float* se    = (const float*)d_in[1];
  const float* curv  = (const float*)d_in[2];
  const float* basis = (const float*)d_in[3];
  const float* gw    = (const float*)d_in[4];
  const float* gb    = (const float*)d_in[5];
  const float* prjw  = (const float*)d_in[6];
  const float* prjb  = (const float*)d_in[7];
  float* out = (float*)d_out;

  char* ws = (char*)d_ws;
  unsigned short* Abf = (unsigned short*)ws;                               // 16 MB
  unsigned short* Wt  = (unsigned short*)(ws + (size_t)16 * 1024 * 1024);  // 10 MB

  prep_inputs<<<5376, 256, 0, stream>>>(state, basis, prjw, Abf, Wt);
  dim3 gg(B_DIM / 128, O_DIM / 64);
  gemm_fused<<<gg, 256, 0, stream>>>(Abf, Wt, se, curv, gw, gb, prjb, out);
}